// Round 13
// baseline (376.835 us; speedup 1.0000x reference)
//
#include <hip/hip_runtime.h>
#include <hip/hip_fp16.h>
#include <math.h>

#define GR 128            // grid resolution
#define NCH 28            // real channels (1 density + 27 SH)
#define NCELL 131072      // 32 x 64 x 64 cells of 4x2x2 voxels, x-fastest

typedef unsigned int uivec4 __attribute__((ext_vector_type(4)));
typedef float fvec4 __attribute__((ext_vector_type(4)));

// ---------------------------------------------------------------------------
// 16-byte voxel (R8-proven):
//   dword0: SH nibbles c0..c7, dword1: c8..c15, dword2: c16..c23
//   dword3: [3:0]=c24 [7:4]=c25 [11:8]=c26 [15:12]=e, [31:16]=density fp16
// SH coef value = (n - 8) * 2^(e-14)
// ---------------------------------------------------------------------------

__device__ __forceinline__ float sigmoidf_(float x) {
    return 1.0f / (1.0f + expf(-x));
}
__device__ __forceinline__ __half2 u2h2(unsigned int u) {
    return *reinterpret_cast<__half2*>(&u);
}

// quantize a point to 7.9 fixed-point voxel coords (identical in hist/scatter)
__device__ __forceinline__ void quant_point(const float* __restrict__ xyz, int i,
                                            unsigned int& ux, unsigned int& uy,
                                            unsigned int& uz) {
    const float kk = (1.0f / 1.5f) * 0.5f * (float)(GR - 1);
    const float cc = 0.5f * (float)(GR - 1);
    float fx = fminf(fmaxf(fmaf(xyz[3*i+0], kk, cc), 0.0f), (float)(GR - 1));
    float fy = fminf(fmaxf(fmaf(xyz[3*i+1], kk, cc), 0.0f), (float)(GR - 1));
    float fz = fminf(fmaxf(fmaf(xyz[3*i+2], kk, cc), 0.0f), (float)(GR - 1));
    ux = (unsigned int)(int)rintf(fx * 512.0f);   // <= 65024
    uy = (unsigned int)(int)rintf(fy * 512.0f);
    uz = (unsigned int)(int)rintf(fz * 512.0f);
}
// cell id: x-chunk (4 voxels) fastest, then y (2), then z (2)
__device__ __forceinline__ unsigned int cell_of(unsigned int ux, unsigned int uy,
                                                unsigned int uz) {
    return ((uz >> 10) << 11) | ((uy >> 10) << 5) | (ux >> 11);
}

// ---------------------------------------------------------------------------
// Pack (C,D,H,W) fp32 -> 16 B voxels. 2 voxels per thread (proven R8 version).
// ---------------------------------------------------------------------------
__global__ __launch_bounds__(256) void pack_kernel(
    const float* __restrict__ dens,
    const float* __restrict__ sh,
    uint4* __restrict__ vol,
    int V)
{
    int t = blockIdx.x * blockDim.x + threadIdx.x;
    int v0 = t * 2;
    if (v0 >= V) return;

    float2 dd = *reinterpret_cast<const float2*>(dens + v0);
    float sa[27], sb[27];
#pragma unroll
    for (int q = 0; q < 27; ++q) {
        float2 s2 = *reinterpret_cast<const float2*>(sh + (size_t)q * (size_t)V + v0);
        sa[q] = s2.x;
        sb[q] = s2.y;
    }

#pragma unroll
    for (int j = 0; j < 2; ++j) {
        const float* sv = (j == 0) ? sa : sb;
        float dv = (j == 0) ? dd.x : dd.y;

        float mp = 0.0f, mn = 0.0f;
#pragma unroll
        for (int q = 0; q < 27; ++q) {
            float x = sv[q];
            mp = fmaxf(mp, x);
            mn = fmaxf(mn, -x);
        }
        float tq = fmaxf(fmaxf(mp * (1.0f / 7.0f), mn * 0.125f), 7.5e-9f);
        int ex = (int)((__float_as_uint(tq) >> 23) & 0xFFu) - 126;
        int e = min(max(ex + 14, 0), 15);
        float invf = __uint_as_float((unsigned int)(141 - e) << 23);  // 2^(14-e)

        unsigned int w[4];
#pragma unroll
        for (int d = 0; d < 3; ++d) {
            unsigned int acc = 0;
#pragma unroll
            for (int b = 0; b < 8; ++b) {
                int n = (int)rintf(sv[8 * d + b] * invf) + 8;
                n = min(max(n, 0), 15);
                acc |= (unsigned int)n << (4 * b);
            }
            w[d] = acc;
        }
        int n24 = min(max((int)rintf(sv[24] * invf) + 8, 0), 15);
        int n25 = min(max((int)rintf(sv[25] * invf) + 8, 0), 15);
        int n26 = min(max((int)rintf(sv[26] * invf) + 8, 0), 15);
        unsigned int dh = (unsigned int)__half_as_ushort(__float2half_rn(dv));
        w[3] = (unsigned int)n24 | ((unsigned int)n25 << 4) | ((unsigned int)n26 << 8)
             | ((unsigned int)e << 12) | (dh << 16);

        vol[v0 + j] = make_uint4(w[0], w[1], w[2], w[3]);
    }
}

// ---------------------------------------------------------------------------
// Shade 8 fetched corners -> {density, r, g, b}  (R8-proven math).
// ---------------------------------------------------------------------------
__device__ __forceinline__ fvec4 shade_eval(
    uint4 c000, uint4 c001, uint4 c010, uint4 c011,
    uint4 c100, uint4 c101, uint4 c110, uint4 c111,
    float wx1, float wy1, float wz1,
    float dxv, float dyv, float dzv)
{
    float wx0 = 1.0f - wx1, wy0 = 1.0f - wy1, wz0 = 1.0f - wz1;
    float w000 = wz0 * wy0 * wx0, w001 = wz0 * wy0 * wx1;
    float w010 = wz0 * wy1 * wx0, w011 = wz0 * wy1 * wx1;
    float w100 = wz1 * wy0 * wx0, w101 = wz1 * wy0 * wx1;
    float w110 = wz1 * wy1 * wx0, w111 = wz1 * wy1 * wx1;

    __half2 acc2[15];
#pragma unroll
    for (int p = 0; p < 15; ++p) acc2[p] = u2h2(0u);
    float G = 0.0f, accd = 0.0f;

    #define NIB4(DW, O)                                                        \
    {                                                                          \
        acc2[(O)+0] = __hfma2(g2, u2h2((((DW) << 6) & 0x03C003C0u) | 0x3C003C00u), acc2[(O)+0]); \
        acc2[(O)+1] = __hfma2(g2, u2h2((((DW) << 2) & 0x03C003C0u) | 0x3C003C00u), acc2[(O)+1]); \
        acc2[(O)+2] = __hfma2(g2, u2h2((((DW) >> 2) & 0x03C003C0u) | 0x3C003C00u), acc2[(O)+2]); \
        acc2[(O)+3] = __hfma2(g2, u2h2((((DW) >> 6) & 0x03C003C0u) | 0x3C003C00u), acc2[(O)+3]); \
    }
    #define NIB3(DW, O)                                                        \
    {                                                                          \
        acc2[(O)+0] = __hfma2(g2, u2h2((((DW) << 6) & 0x03C003C0u) | 0x3C003C00u), acc2[(O)+0]); \
        acc2[(O)+1] = __hfma2(g2, u2h2((((DW) << 2) & 0x03C003C0u) | 0x3C003C00u), acc2[(O)+1]); \
        acc2[(O)+2] = __hfma2(g2, u2h2((((DW) >> 2) & 0x03C003C0u) | 0x3C003C00u), acc2[(O)+2]); \
    }
    #define CORNER(C, W)                                                       \
    {                                                                          \
        float w_ = (W);                                                        \
        unsigned int e_ = ((C).w >> 12) & 0xFu;                                \
        float f_ = __uint_as_float((113u + e_) << 23);   /* 2^(e-14) */        \
        float g_ = w_ * f_;                                                    \
        G += g_;                                                               \
        accd = fmaf(w_, __half2float(__ushort_as_half((unsigned short)((C).w >> 16))), accd); \
        __half2 g2 = __float2half2_rn(g_);                                     \
        NIB4((C).x, 0) NIB4((C).y, 4) NIB4((C).z, 8) NIB3((C).w, 12)           \
    }

    CORNER(c000, w000) CORNER(c001, w001) CORNER(c010, w010) CORNER(c011, w011)
    CORNER(c100, w100) CORNER(c101, w101) CORNER(c110, w110) CORNER(c111, w111)
    #undef CORNER
    #undef NIB4
    #undef NIB3

    float c24G = 24.0f * G;
    float sch[27];
#pragma unroll
    for (int d = 0; d < 3; ++d) {
#pragma unroll
        for (int p = 0; p < 4; ++p) {
            float2 f2 = __half22float2(acc2[d * 4 + p]);
            sch[8 * d + p]     = fmaf(16.0f, f2.x, -c24G);
            sch[8 * d + p + 4] = fmaf(16.0f, f2.y, -c24G);
        }
    }
#pragma unroll
    for (int p = 0; p < 3; ++p) {
        float2 f2 = __half22float2(acc2[12 + p]);
        sch[24 + p] = fmaf(16.0f, f2.x, -c24G);
    }

    float xx = dxv*dxv, yy = dyv*dyv, zz = dzv*dzv;
    float bs[9];
    bs[0] = 0.28209479177387814f;
    bs[1] = -0.4886025119029199f * dyv;
    bs[2] =  0.4886025119029199f * dzv;
    bs[3] = -0.4886025119029199f * dxv;
    bs[4] =  1.0925484305920792f * dxv * dyv;
    bs[5] = -1.0925484305920792f * dyv * dzv;
    bs[6] =  0.31539156525252005f * (2.0f*zz - xx - yy);
    bs[7] = -1.0925484305920792f * dxv * dzv;
    bs[8] =  0.5462742152960396f * (xx - yy);

    fvec4 res;
    res.x = fmaxf(accd, 0.0f);
#pragma unroll
    for (int ch = 0; ch < 3; ++ch) {
        float sm = 0.0f;
#pragma unroll
        for (int q = 0; q < 9; ++q) sm = fmaf(sch[ch*9 + q], bs[q], sm);
        if (ch == 0) res.y = sigmoidf_(sm);
        else if (ch == 1) res.z = sigmoidf_(sm);
        else res.w = sigmoidf_(sm);
    }
    return res;
}

// ---------------------------------------------------------------------------
// counting sort: zero, hist, 3-step exact scan, scatter
// ---------------------------------------------------------------------------
__global__ __launch_bounds__(256) void zero_kernel(unsigned int* __restrict__ p, int n) {
    int i = blockIdx.x * blockDim.x + threadIdx.x;
    if (i < n) p[i] = 0u;
}

__global__ __launch_bounds__(256) void hist_kernel(
    const float* __restrict__ xyz, unsigned int* __restrict__ cnt, int N)
{
    int i = blockIdx.x * blockDim.x + threadIdx.x;
    if (i >= N) return;
    unsigned int ux, uy, uz;
    quant_point(xyz, i, ux, uy, uz);
    atomicAdd(&cnt[cell_of(ux, uy, uz)], 1u);
}

__global__ __launch_bounds__(256) void scanA_kernel(
    const unsigned int* __restrict__ cnt,
    unsigned int* __restrict__ excl,      // per-block exclusive scan
    unsigned int* __restrict__ bsum)      // per-block totals (512)
{
    __shared__ unsigned int tmp[256];
    int t = (int)threadIdx.x;
    int g = blockIdx.x * 256 + t;
    unsigned int v = cnt[g];
    tmp[t] = v;
    __syncthreads();
    for (int off = 1; off < 256; off <<= 1) {
        unsigned int u = (t >= off) ? tmp[t - off] : 0u;
        __syncthreads();
        tmp[t] += u;
        __syncthreads();
    }
    excl[g] = tmp[t] - v;
    if (t == 255) bsum[blockIdx.x] = tmp[255];
}

__global__ __launch_bounds__(512) void scanB_kernel(
    const unsigned int* __restrict__ bsum, unsigned int* __restrict__ boff)
{
    __shared__ unsigned int tmp[512];
    int t = (int)threadIdx.x;
    unsigned int v = bsum[t];
    tmp[t] = v;
    __syncthreads();
    for (int off = 1; off < 512; off <<= 1) {
        unsigned int u = (t >= off) ? tmp[t - off] : 0u;
        __syncthreads();
        tmp[t] += u;
        __syncthreads();
    }
    boff[t] = tmp[t] - v;
}

__global__ __launch_bounds__(256) void scanC_kernel(
    unsigned int* __restrict__ excl, const unsigned int* __restrict__ boff)
{
    int g = blockIdx.x * 256 + (int)threadIdx.x;
    excl[g] += boff[blockIdx.x];
}

__global__ __launch_bounds__(256) void scatter_kernel(
    const float* __restrict__ xyz, const float* __restrict__ vdirs,
    unsigned int* __restrict__ cursors,   // exclusive starts; consumed
    uint4* __restrict__ recs, int N)
{
    int i = blockIdx.x * blockDim.x + threadIdx.x;
    if (i >= N) return;
    unsigned int ux, uy, uz;
    quant_point(xyz, i, ux, uy, uz);
    unsigned int pos = atomicAdd(&cursors[cell_of(ux, uy, uz)], 1u);

    unsigned int hx = (unsigned int)__half_as_ushort(__float2half_rn(vdirs[3*i+0]));
    unsigned int hy = (unsigned int)__half_as_ushort(__float2half_rn(vdirs[3*i+1]));
    unsigned int hz = (unsigned int)__half_as_ushort(__float2half_rn(vdirs[3*i+2]));
    uivec4 rec;
    rec.x = ux | (uy << 16);
    rec.y = uz | (hx << 16);
    rec.z = hy | (hz << 16);
    rec.w = (unsigned int)i;
    __builtin_nontemporal_store(rec, (uivec4*)(recs + pos));
}

// ---------------------------------------------------------------------------
// Sorted sample: dense slots, wave spans ~4 adjacent 4x2x2 cells so each
// corner-load instruction touches ~10-14 cache lines instead of ~62.
// Result written as ONE nontemporal float4 to resbuf[idx]; split kernel
// unpacks coalesced.
// ---------------------------------------------------------------------------
__global__ __launch_bounds__(256) void sample_sorted_kernel(
    const uint4* __restrict__ recs,
    const uint4* __restrict__ vol,
    fvec4* __restrict__ resbuf,
    int N, int nwg)
{
    // bijective XCD-chunked swizzle (m204)
    int bid = blockIdx.x;
    int q = nwg >> 3, r = nwg & 7;
    int xcd = bid & 7, k = bid >> 3;
    int swz = (xcd < r ? xcd * (q + 1) : r * (q + 1) + (xcd - r) * q) + k;
    int i = swz * 256 + (int)threadIdx.x;
    if (i >= N) return;

    uivec4 Rv = __builtin_nontemporal_load((const uivec4*)(recs + i));
    unsigned int ux = Rv.x & 0xFFFFu, uy = Rv.x >> 16;
    unsigned int uz = Rv.y & 0xFFFFu;
    int x0 = (int)(ux >> 9), y0 = (int)(uy >> 9), z0 = (int)(uz >> 9);
    float wx1 = (float)(ux & 511u) * (1.0f / 512.0f);
    float wy1 = (float)(uy & 511u) * (1.0f / 512.0f);
    float wz1 = (float)(uz & 511u) * (1.0f / 512.0f);
    int x1 = min(x0 + 1, GR - 1);
    int y1 = min(y0 + 1, GR - 1);
    int z1 = min(z0 + 1, GR - 1);

    int r00 = (z0 * GR + y0) * GR, r01 = (z0 * GR + y1) * GR;
    int r10 = (z1 * GR + y0) * GR, r11 = (z1 * GR + y1) * GR;
    uint4 c000 = vol[r00 + x0];
    uint4 c001 = vol[r00 + x1];
    uint4 c010 = vol[r01 + x0];
    uint4 c011 = vol[r01 + x1];
    uint4 c100 = vol[r10 + x0];
    uint4 c101 = vol[r10 + x1];
    uint4 c110 = vol[r11 + x0];
    uint4 c111 = vol[r11 + x1];

    float dxv = __half2float(__ushort_as_half((unsigned short)(Rv.y >> 16)));
    float dyv = __half2float(__ushort_as_half((unsigned short)(Rv.z & 0xFFFFu)));
    float dzv = __half2float(__ushort_as_half((unsigned short)(Rv.z >> 16)));

    fvec4 res = shade_eval(c000, c001, c010, c011, c100, c101, c110, c111,
                           wx1, wy1, wz1, dxv, dyv, dzv);
    __builtin_nontemporal_store(res, resbuf + Rv.w);
}

__global__ __launch_bounds__(256) void split_kernel(
    const fvec4* __restrict__ resbuf, float* __restrict__ out, int N)
{
    int i = blockIdx.x * blockDim.x + threadIdx.x;
    if (i >= N) return;
    fvec4 v = __builtin_nontemporal_load(resbuf + i);
    out[i] = v.x;
    size_t o = (size_t)N + 3*(size_t)i;
    out[o + 0] = v.y;
    out[o + 1] = v.z;
    out[o + 2] = v.w;
}

// ---------------------------------------------------------------------------
// Mid fallback: unsorted sample of 16 B voxels (R8-proven, 204 µs total).
// ---------------------------------------------------------------------------
__global__ __launch_bounds__(256) void sample_kernel(
    const float* __restrict__ xyz,
    const float* __restrict__ vdirs,
    const uint4* __restrict__ vol,
    float* __restrict__ out,
    int N)
{
    int i = blockIdx.x * blockDim.x + threadIdx.x;
    if (i >= N) return;

    const float kk = (1.0f / 1.5f) * 0.5f * (float)(GR - 1);
    const float cc = 0.5f * (float)(GR - 1);
    float fx = fminf(fmaxf(fmaf(xyz[3*i+0], kk, cc), 0.0f), (float)(GR - 1));
    float fy = fminf(fmaxf(fmaf(xyz[3*i+1], kk, cc), 0.0f), (float)(GR - 1));
    float fz = fminf(fmaxf(fmaf(xyz[3*i+2], kk, cc), 0.0f), (float)(GR - 1));
    int x0 = (int)fx, y0 = (int)fy, z0 = (int)fz;
    float wx1 = fx - (float)x0, wy1 = fy - (float)y0, wz1 = fz - (float)z0;
    int x1 = min(x0 + 1, GR - 1);
    int y1 = min(y0 + 1, GR - 1);
    int z1 = min(z0 + 1, GR - 1);

    int r00 = (z0 * GR + y0) * GR, r01 = (z0 * GR + y1) * GR;
    int r10 = (z1 * GR + y0) * GR, r11 = (z1 * GR + y1) * GR;
    fvec4 res = shade_eval(vol[r00 + x0], vol[r00 + x1], vol[r01 + x0], vol[r01 + x1],
                           vol[r10 + x0], vol[r10 + x1], vol[r11 + x0], vol[r11 + x1],
                           wx1, wy1, wz1,
                           vdirs[3*i+0], vdirs[3*i+1], vdirs[3*i+2]);
    out[i] = res.x;
    size_t o = (size_t)N + 3*(size_t)i;
    out[o + 0] = res.y;
    out[o + 1] = res.z;
    out[o + 2] = res.w;
}

// ---------------------------------------------------------------------------
// Tiny-ws fallback: direct fp32 channel-major sampling.
// ---------------------------------------------------------------------------
__global__ __launch_bounds__(256) void sample_direct_kernel(
    const float* __restrict__ xyz,
    const float* __restrict__ vdirs,
    const float* __restrict__ dens,
    const float* __restrict__ sh,
    float* __restrict__ out,
    int N)
{
    int i = blockIdx.x * blockDim.x + threadIdx.x;
    if (i >= N) return;

    const float kk = (1.0f / 1.5f) * 0.5f * (float)(GR - 1);
    const float cc = 0.5f * (float)(GR - 1);
    float fx = fminf(fmaxf(fmaf(xyz[3*i+0], kk, cc), 0.0f), (float)(GR - 1));
    float fy = fminf(fmaxf(fmaf(xyz[3*i+1], kk, cc), 0.0f), (float)(GR - 1));
    float fz = fminf(fmaxf(fmaf(xyz[3*i+2], kk, cc), 0.0f), (float)(GR - 1));
    float x0f = floorf(fx), y0f = floorf(fy), z0f = floorf(fz);
    float wx1 = fx - x0f, wy1 = fy - y0f, wz1 = fz - z0f;
    int x0 = (int)x0f, y0 = (int)y0f, z0 = (int)z0f;
    float wx[2] = { 1.0f - wx1, wx1 };
    float wy[2] = { 1.0f - wy1, wy1 };
    float wz[2] = { 1.0f - wz1, wz1 };
    int xi[2] = { x0, min(x0 + 1, GR-1) };
    int yi[2] = { y0, min(y0 + 1, GR-1) };
    int zi[2] = { z0, min(z0 + 1, GR-1) };

    const size_t V = (size_t)GR * GR * GR;
    float acc[NCH];
#pragma unroll
    for (int c = 0; c < NCH; ++c) acc[c] = 0.0f;

#pragma unroll
    for (int dz = 0; dz < 2; ++dz)
#pragma unroll
        for (int dy = 0; dy < 2; ++dy)
#pragma unroll
            for (int dx = 0; dx < 2; ++dx) {
                float w = wz[dz] * wy[dy] * wx[dx];
                size_t vox = (((size_t)zi[dz] * GR) + yi[dy]) * GR + xi[dx];
                acc[0] = fmaf(w, dens[vox], acc[0]);
#pragma unroll
                for (int c = 0; c < 27; ++c)
                    acc[1 + c] = fmaf(w, sh[(size_t)c * V + vox], acc[1 + c]);
            }

    float dxv = vdirs[3*i+0], dyv = vdirs[3*i+1], dzv = vdirs[3*i+2];
    float xx = dxv*dxv, yy = dyv*dyv, zz = dzv*dzv;
    float b[9];
    b[0] = 0.28209479177387814f;
    b[1] = -0.4886025119029199f * dyv;
    b[2] =  0.4886025119029199f * dzv;
    b[3] = -0.4886025119029199f * dxv;
    b[4] =  1.0925484305920792f * dxv * dyv;
    b[5] = -1.0925484305920792f * dyv * dzv;
    b[6] =  0.31539156525252005f * (2.0f*zz - xx - yy);
    b[7] = -1.0925484305920792f * dxv * dzv;
    b[8] =  0.5462742152960396f * (xx - yy);

    out[i] = fmaxf(acc[0], 0.0f);
#pragma unroll
    for (int c = 0; c < 3; ++c) {
        float sm = 0.0f;
#pragma unroll
        for (int q = 0; q < 9; ++q) sm = fmaf(acc[1 + c*9 + q], b[q], sm);
        out[(size_t)N + 3*(size_t)i + c] = sigmoidf_(sm);
    }
}

extern "C" void kernel_launch(void* const* d_in, const int* in_sizes, int n_in,
                              void* d_out, int out_size, void* d_ws, size_t ws_size,
                              hipStream_t stream) {
    const float* xyz   = (const float*)d_in[0];
    const float* vdirs = (const float*)d_in[1];
    const float* dens  = (const float*)d_in[2];
    const float* sh    = (const float*)d_in[3];
    float* out = (float*)d_out;

    int N = in_sizes[0] / 3;
    const int V = GR * GR * GR;

    size_t off_vol  = 0;
    size_t sz_vol   = (size_t)V * 16;                        // 33.5 MB
    size_t off_recs = (off_vol + sz_vol + 255) & ~(size_t)255;
    size_t sz_recs  = (size_t)N * 16;                        // 32 MB
    size_t off_res  = (off_recs + sz_recs + 255) & ~(size_t)255;
    size_t sz_res   = (size_t)N * 16;                        // 32 MB
    size_t off_cnt  = (off_res + sz_res + 255) & ~(size_t)255;
    size_t sz_cnt   = (size_t)NCELL * 4;                     // 0.5 MB
    size_t off_bs   = (off_cnt + sz_cnt + 255) & ~(size_t)255;
    size_t sz_bs    = 512 * 4 * 2;                           // bsum + boff
    size_t need_full = off_bs + sz_bs;
    size_t need_mid  = sz_vol;

    if (ws_size >= need_full) {
        char* ws = (char*)d_ws;
        uint4*        vol     = (uint4*)(ws + off_vol);
        uint4*        recs    = (uint4*)(ws + off_recs);
        fvec4*        resbuf  = (fvec4*)(ws + off_res);
        unsigned int* cnt     = (unsigned int*)(ws + off_cnt);
        unsigned int* bsum    = (unsigned int*)(ws + off_bs);
        unsigned int* boff    = bsum + 512;

        int nwg = (N + 255) / 256;

        pack_kernel<<<(V / 2 + 255) / 256, 256, 0, stream>>>(dens, sh, vol, V);
        zero_kernel<<<NCELL / 256, 256, 0, stream>>>(cnt, NCELL);
        hist_kernel<<<nwg, 256, 0, stream>>>(xyz, cnt, N);
        scanA_kernel<<<NCELL / 256, 256, 0, stream>>>(cnt, cnt, bsum);   // in-place excl scan per block
        scanB_kernel<<<1, 512, 0, stream>>>(bsum, boff);
        scanC_kernel<<<NCELL / 256, 256, 0, stream>>>(cnt, boff);
        scatter_kernel<<<nwg, 256, 0, stream>>>(xyz, vdirs, cnt, recs, N);
        sample_sorted_kernel<<<nwg, 256, 0, stream>>>(recs, vol, resbuf, N, nwg);
        split_kernel<<<nwg, 256, 0, stream>>>(resbuf, out, N);
    } else if (ws_size >= need_mid) {
        uint4* vol = (uint4*)d_ws;
        pack_kernel<<<(V / 2 + 255) / 256, 256, 0, stream>>>(dens, sh, vol, V);
        sample_kernel<<<(N + 255) / 256, 256, 0, stream>>>(xyz, vdirs, vol, out, N);
    } else {
        sample_direct_kernel<<<(N + 255) / 256, 256, 0, stream>>>(xyz, vdirs, dens, sh, out, N);
    }
}

// Round 14
// 217.320 us; speedup vs baseline: 1.7340x; 1.7340x over previous
//
#include <hip/hip_runtime.h>
#include <hip/hip_fp16.h>
#include <math.h>

#define GR 128            // grid resolution
#define NCH 28            // real channels (1 density + 27 SH)

typedef float fvec4 __attribute__((ext_vector_type(4)));

// ---------------------------------------------------------------------------
// 16-byte voxel (R8-proven):
//   dword0: SH nibbles c0..c7, dword1: c8..c15, dword2: c16..c23
//   dword3: [3:0]=c24 [7:4]=c25 [11:8]=c26 [15:12]=e, [31:16]=density fp16
// SH coef value = (n - 8) * 2^(e-14)
// ---------------------------------------------------------------------------

__device__ __forceinline__ float sigmoidf_(float x) {
    return 1.0f / (1.0f + expf(-x));
}
__device__ __forceinline__ __half2 u2h2(unsigned int u) {
    return *reinterpret_cast<__half2*>(&u);
}

// ---------------------------------------------------------------------------
// Pack (C,D,H,W) fp32 -> 16 B voxels. 2 voxels per thread (proven R8 version).
// ---------------------------------------------------------------------------
__global__ __launch_bounds__(256) void pack_kernel(
    const float* __restrict__ dens,
    const float* __restrict__ sh,
    uint4* __restrict__ vol,
    int V)
{
    int t = blockIdx.x * blockDim.x + threadIdx.x;
    int v0 = t * 2;
    if (v0 >= V) return;

    float2 dd = *reinterpret_cast<const float2*>(dens + v0);
    float sa[27], sb[27];
#pragma unroll
    for (int q = 0; q < 27; ++q) {
        float2 s2 = *reinterpret_cast<const float2*>(sh + (size_t)q * (size_t)V + v0);
        sa[q] = s2.x;
        sb[q] = s2.y;
    }

#pragma unroll
    for (int j = 0; j < 2; ++j) {
        const float* sv = (j == 0) ? sa : sb;
        float dv = (j == 0) ? dd.x : dd.y;

        float mp = 0.0f, mn = 0.0f;
#pragma unroll
        for (int q = 0; q < 27; ++q) {
            float x = sv[q];
            mp = fmaxf(mp, x);
            mn = fmaxf(mn, -x);
        }
        float tq = fmaxf(fmaxf(mp * (1.0f / 7.0f), mn * 0.125f), 7.5e-9f);
        int ex = (int)((__float_as_uint(tq) >> 23) & 0xFFu) - 126;
        int e = min(max(ex + 14, 0), 15);
        float invf = __uint_as_float((unsigned int)(141 - e) << 23);  // 2^(14-e)

        unsigned int w[4];
#pragma unroll
        for (int d = 0; d < 3; ++d) {
            unsigned int acc = 0;
#pragma unroll
            for (int b = 0; b < 8; ++b) {
                int n = (int)rintf(sv[8 * d + b] * invf) + 8;
                n = min(max(n, 0), 15);
                acc |= (unsigned int)n << (4 * b);
            }
            w[d] = acc;
        }
        int n24 = min(max((int)rintf(sv[24] * invf) + 8, 0), 15);
        int n25 = min(max((int)rintf(sv[25] * invf) + 8, 0), 15);
        int n26 = min(max((int)rintf(sv[26] * invf) + 8, 0), 15);
        unsigned int dh = (unsigned int)__half_as_ushort(__float2half_rn(dv));
        w[3] = (unsigned int)n24 | ((unsigned int)n25 << 4) | ((unsigned int)n26 << 8)
             | ((unsigned int)e << 12) | (dh << 16);

        vol[v0 + j] = make_uint4(w[0], w[1], w[2], w[3]);
    }
}

// ---------------------------------------------------------------------------
// Shade 8 fetched corners -> {density, r, g, b}  (R8-proven math).
// ---------------------------------------------------------------------------
__device__ __forceinline__ fvec4 shade_eval(
    uint4 c000, uint4 c001, uint4 c010, uint4 c011,
    uint4 c100, uint4 c101, uint4 c110, uint4 c111,
    float wx1, float wy1, float wz1,
    float dxv, float dyv, float dzv)
{
    float wx0 = 1.0f - wx1, wy0 = 1.0f - wy1, wz0 = 1.0f - wz1;
    float w000 = wz0 * wy0 * wx0, w001 = wz0 * wy0 * wx1;
    float w010 = wz0 * wy1 * wx0, w011 = wz0 * wy1 * wx1;
    float w100 = wz1 * wy0 * wx0, w101 = wz1 * wy0 * wx1;
    float w110 = wz1 * wy1 * wx0, w111 = wz1 * wy1 * wx1;

    __half2 acc2[15];
#pragma unroll
    for (int p = 0; p < 15; ++p) acc2[p] = u2h2(0u);
    float G = 0.0f, accd = 0.0f;

    #define NIB4(DW, O)                                                        \
    {                                                                          \
        acc2[(O)+0] = __hfma2(g2, u2h2((((DW) << 6) & 0x03C003C0u) | 0x3C003C00u), acc2[(O)+0]); \
        acc2[(O)+1] = __hfma2(g2, u2h2((((DW) << 2) & 0x03C003C0u) | 0x3C003C00u), acc2[(O)+1]); \
        acc2[(O)+2] = __hfma2(g2, u2h2((((DW) >> 2) & 0x03C003C0u) | 0x3C003C00u), acc2[(O)+2]); \
        acc2[(O)+3] = __hfma2(g2, u2h2((((DW) >> 6) & 0x03C003C0u) | 0x3C003C00u), acc2[(O)+3]); \
    }
    #define NIB3(DW, O)                                                        \
    {                                                                          \
        acc2[(O)+0] = __hfma2(g2, u2h2((((DW) << 6) & 0x03C003C0u) | 0x3C003C00u), acc2[(O)+0]); \
        acc2[(O)+1] = __hfma2(g2, u2h2((((DW) << 2) & 0x03C003C0u) | 0x3C003C00u), acc2[(O)+1]); \
        acc2[(O)+2] = __hfma2(g2, u2h2((((DW) >> 2) & 0x03C003C0u) | 0x3C003C00u), acc2[(O)+2]); \
    }
    #define CORNER(C, W)                                                       \
    {                                                                          \
        float w_ = (W);                                                        \
        unsigned int e_ = ((C).w >> 12) & 0xFu;                                \
        float f_ = __uint_as_float((113u + e_) << 23);   /* 2^(e-14) */        \
        float g_ = w_ * f_;                                                    \
        G += g_;                                                               \
        accd = fmaf(w_, __half2float(__ushort_as_half((unsigned short)((C).w >> 16))), accd); \
        __half2 g2 = __float2half2_rn(g_);                                     \
        NIB4((C).x, 0) NIB4((C).y, 4) NIB4((C).z, 8) NIB3((C).w, 12)           \
    }

    CORNER(c000, w000) CORNER(c001, w001) CORNER(c010, w010) CORNER(c011, w011)
    CORNER(c100, w100) CORNER(c101, w101) CORNER(c110, w110) CORNER(c111, w111)
    #undef CORNER
    #undef NIB4
    #undef NIB3

    float c24G = 24.0f * G;
    float sch[27];
#pragma unroll
    for (int d = 0; d < 3; ++d) {
#pragma unroll
        for (int p = 0; p < 4; ++p) {
            float2 f2 = __half22float2(acc2[d * 4 + p]);
            sch[8 * d + p]     = fmaf(16.0f, f2.x, -c24G);
            sch[8 * d + p + 4] = fmaf(16.0f, f2.y, -c24G);
        }
    }
#pragma unroll
    for (int p = 0; p < 3; ++p) {
        float2 f2 = __half22float2(acc2[12 + p]);
        sch[24 + p] = fmaf(16.0f, f2.x, -c24G);
    }

    float xx = dxv*dxv, yy = dyv*dyv, zz = dzv*dzv;
    float bs[9];
    bs[0] = 0.28209479177387814f;
    bs[1] = -0.4886025119029199f * dyv;
    bs[2] =  0.4886025119029199f * dzv;
    bs[3] = -0.4886025119029199f * dxv;
    bs[4] =  1.0925484305920792f * dxv * dyv;
    bs[5] = -1.0925484305920792f * dyv * dzv;
    bs[6] =  0.31539156525252005f * (2.0f*zz - xx - yy);
    bs[7] = -1.0925484305920792f * dxv * dzv;
    bs[8] =  0.5462742152960396f * (xx - yy);

    fvec4 res;
    res.x = fmaxf(accd, 0.0f);
#pragma unroll
    for (int ch = 0; ch < 3; ++ch) {
        float sm = 0.0f;
#pragma unroll
        for (int q = 0; q < 9; ++q) sm = fmaf(sch[ch*9 + q], bs[q], sm);
        if (ch == 0) res.y = sigmoidf_(sm);
        else if (ch == 1) res.z = sigmoidf_(sm);
        else res.w = sigmoidf_(sm);
    }
    return res;
}

// address setup: quantized coords -> 8 corner row bases + fractions
__device__ __forceinline__ void corner_setup(
    const float* __restrict__ xyz, int i,
    int& b000, int& b001, int& b010, int& b011,
    int& b100, int& b101, int& b110, int& b111,
    float& wx1, float& wy1, float& wz1)
{
    const float kk = (1.0f / 1.5f) * 0.5f * (float)(GR - 1);
    const float cc = 0.5f * (float)(GR - 1);
    float fx = fminf(fmaxf(fmaf(xyz[3*i+0], kk, cc), 0.0f), (float)(GR - 1));
    float fy = fminf(fmaxf(fmaf(xyz[3*i+1], kk, cc), 0.0f), (float)(GR - 1));
    float fz = fminf(fmaxf(fmaf(xyz[3*i+2], kk, cc), 0.0f), (float)(GR - 1));
    int x0 = (int)fx, y0 = (int)fy, z0 = (int)fz;
    wx1 = fx - (float)x0; wy1 = fy - (float)y0; wz1 = fz - (float)z0;
    int x1 = min(x0 + 1, GR - 1);
    int y1 = min(y0 + 1, GR - 1);
    int z1 = min(z0 + 1, GR - 1);
    int r00 = (z0 * GR + y0) * GR, r01 = (z0 * GR + y1) * GR;
    int r10 = (z1 * GR + y0) * GR, r11 = (z1 * GR + y1) * GR;
    b000 = r00 + x0; b001 = r00 + x1;
    b010 = r01 + x0; b011 = r01 + x1;
    b100 = r10 + x0; b101 = r10 + x1;
    b110 = r11 + x0; b111 = r11 + x1;
}

// ---------------------------------------------------------------------------
// Main: 2 points per thread, all 16 corner loads issued before any shading
// (doubles per-wave memory-level parallelism). Outputs coalesced by i.
// ---------------------------------------------------------------------------
__global__ __launch_bounds__(256) void sample2_kernel(
    const float* __restrict__ xyz,
    const float* __restrict__ vdirs,
    const uint4* __restrict__ vol,
    float* __restrict__ out,
    int N)
{
    int iA = blockIdx.x * 512 + (int)threadIdx.x;
    int iB = iA + 256;
    bool vA = (iA < N), vB = (iB < N);
    if (!vA) return;

    int a0,a1,a2,a3,a4,a5,a6,a7;
    float awx, awy, awz;
    corner_setup(xyz, iA, a0,a1,a2,a3,a4,a5,a6,a7, awx, awy, awz);

    int b0,b1,b2,b3,b4,b5,b6,b7;
    float bwx = 0, bwy = 0, bwz = 0;
    if (vB) corner_setup(xyz, iB, b0,b1,b2,b3,b4,b5,b6,b7, bwx, bwy, bwz);
    else { b0=b1=b2=b3=b4=b5=b6=b7=a0; }

    // issue all 16 loads back-to-back
    uint4 A0 = vol[a0], A1 = vol[a1], A2 = vol[a2], A3 = vol[a3];
    uint4 A4 = vol[a4], A5 = vol[a5], A6 = vol[a6], A7 = vol[a7];
    uint4 B0 = vol[b0], B1 = vol[b1], B2 = vol[b2], B3 = vol[b3];
    uint4 B4 = vol[b4], B5 = vol[b5], B6 = vol[b6], B7 = vol[b7];

    {
        fvec4 res = shade_eval(A0, A1, A2, A3, A4, A5, A6, A7,
                               awx, awy, awz,
                               vdirs[3*iA+0], vdirs[3*iA+1], vdirs[3*iA+2]);
        out[iA] = res.x;
        size_t o = (size_t)N + 3*(size_t)iA;
        out[o + 0] = res.y;
        out[o + 1] = res.z;
        out[o + 2] = res.w;
    }
    if (vB) {
        fvec4 res = shade_eval(B0, B1, B2, B3, B4, B5, B6, B7,
                               bwx, bwy, bwz,
                               vdirs[3*iB+0], vdirs[3*iB+1], vdirs[3*iB+2]);
        out[iB] = res.x;
        size_t o = (size_t)N + 3*(size_t)iB;
        out[o + 0] = res.y;
        out[o + 1] = res.z;
        out[o + 2] = res.w;
    }
}

// ---------------------------------------------------------------------------
// Tiny-ws fallback: direct fp32 channel-major sampling.
// ---------------------------------------------------------------------------
__global__ __launch_bounds__(256) void sample_direct_kernel(
    const float* __restrict__ xyz,
    const float* __restrict__ vdirs,
    const float* __restrict__ dens,
    const float* __restrict__ sh,
    float* __restrict__ out,
    int N)
{
    int i = blockIdx.x * blockDim.x + threadIdx.x;
    if (i >= N) return;

    const float kk = (1.0f / 1.5f) * 0.5f * (float)(GR - 1);
    const float cc = 0.5f * (float)(GR - 1);
    float fx = fminf(fmaxf(fmaf(xyz[3*i+0], kk, cc), 0.0f), (float)(GR - 1));
    float fy = fminf(fmaxf(fmaf(xyz[3*i+1], kk, cc), 0.0f), (float)(GR - 1));
    float fz = fminf(fmaxf(fmaf(xyz[3*i+2], kk, cc), 0.0f), (float)(GR - 1));
    float x0f = floorf(fx), y0f = floorf(fy), z0f = floorf(fz);
    float wx1 = fx - x0f, wy1 = fy - y0f, wz1 = fz - z0f;
    int x0 = (int)x0f, y0 = (int)y0f, z0 = (int)z0f;
    float wx[2] = { 1.0f - wx1, wx1 };
    float wy[2] = { 1.0f - wy1, wy1 };
    float wz[2] = { 1.0f - wz1, wz1 };
    int xi[2] = { x0, min(x0 + 1, GR-1) };
    int yi[2] = { y0, min(y0 + 1, GR-1) };
    int zi[2] = { z0, min(z0 + 1, GR-1) };

    const size_t V = (size_t)GR * GR * GR;
    float acc[NCH];
#pragma unroll
    for (int c = 0; c < NCH; ++c) acc[c] = 0.0f;

#pragma unroll
    for (int dz = 0; dz < 2; ++dz)
#pragma unroll
        for (int dy = 0; dy < 2; ++dy)
#pragma unroll
            for (int dx = 0; dx < 2; ++dx) {
                float w = wz[dz] * wy[dy] * wx[dx];
                size_t vox = (((size_t)zi[dz] * GR) + yi[dy]) * GR + xi[dx];
                acc[0] = fmaf(w, dens[vox], acc[0]);
#pragma unroll
                for (int c = 0; c < 27; ++c)
                    acc[1 + c] = fmaf(w, sh[(size_t)c * V + vox], acc[1 + c]);
            }

    float dxv = vdirs[3*i+0], dyv = vdirs[3*i+1], dzv = vdirs[3*i+2];
    float xx = dxv*dxv, yy = dyv*dyv, zz = dzv*dzv;
    float b[9];
    b[0] = 0.28209479177387814f;
    b[1] = -0.4886025119029199f * dyv;
    b[2] =  0.4886025119029199f * dzv;
    b[3] = -0.4886025119029199f * dxv;
    b[4] =  1.0925484305920792f * dxv * dyv;
    b[5] = -1.0925484305920792f * dyv * dzv;
    b[6] =  0.31539156525252005f * (2.0f*zz - xx - yy);
    b[7] = -1.0925484305920792f * dxv * dzv;
    b[8] =  0.5462742152960396f * (xx - yy);

    out[i] = fmaxf(acc[0], 0.0f);
#pragma unroll
    for (int c = 0; c < 3; ++c) {
        float sm = 0.0f;
#pragma unroll
        for (int q = 0; q < 9; ++q) sm = fmaf(acc[1 + c*9 + q], b[q], sm);
        out[(size_t)N + 3*(size_t)i + c] = sigmoidf_(sm);
    }
}

extern "C" void kernel_launch(void* const* d_in, const int* in_sizes, int n_in,
                              void* d_out, int out_size, void* d_ws, size_t ws_size,
                              hipStream_t stream) {
    const float* xyz   = (const float*)d_in[0];
    const float* vdirs = (const float*)d_in[1];
    const float* dens  = (const float*)d_in[2];
    const float* sh    = (const float*)d_in[3];
    float* out = (float*)d_out;

    int N = in_sizes[0] / 3;
    const int V = GR * GR * GR;
    size_t need = (size_t)V * 16;        // 33.5 MB packed volume

    if (ws_size >= need) {
        uint4* vol = (uint4*)d_ws;
        pack_kernel<<<(V / 2 + 255) / 256, 256, 0, stream>>>(dens, sh, vol, V);
        sample2_kernel<<<(N + 511) / 512, 256, 0, stream>>>(xyz, vdirs, vol, out, N);
    } else {
        sample_direct_kernel<<<(N + 255) / 256, 256, 0, stream>>>(xyz, vdirs, dens, sh, out, N);
    }
}

// Round 15
// 169.462 us; speedup vs baseline: 2.2237x; 1.2824x over previous
//
#include <hip/hip_runtime.h>
#include <hip/hip_fp16.h>
#include <math.h>

#define GR 128            // grid resolution
#define GB 64             // bricks per axis (2x2x2-voxel bricks)
#define NCH 28            // real channels (1 density + 27 SH)

typedef float fvec4 __attribute__((ext_vector_type(4)));

// ---------------------------------------------------------------------------
// 16-byte voxel (R8-proven), stored in 2x2x2-voxel bricks so one brick =
// 8 voxels x 16 B = exactly one 128 B cache line.
//   brick(bx,by,bz) at ((bz*GB+by)*GB+bx)*8 ; voxel offset (z&1)<<2|(y&1)<<1|(x&1)
//   dword0: SH nibbles c0..c7, dword1: c8..c15, dword2: c16..c23
//   dword3: [3:0]=c24 [7:4]=c25 [11:8]=c26 [15:12]=e, [31:16]=density fp16
// SH coef value = (n - 8) * 2^(e-14)
// ---------------------------------------------------------------------------

__device__ __forceinline__ float sigmoidf_(float x) {
    return 1.0f / (1.0f + expf(-x));
}
__device__ __forceinline__ __half2 u2h2(unsigned int u) {
    return *reinterpret_cast<__half2*>(&u);
}
__device__ __forceinline__ int brick_addr(int x, int y, int z) {
    int b = ((z >> 1) * GB + (y >> 1)) * GB + (x >> 1);
    return b * 8 + ((z & 1) << 2) + ((y & 1) << 1) + (x & 1);
}

// ---------------------------------------------------------------------------
// Pack (C,D,H,W) fp32 -> 16 B voxels in brick order. 2 voxels per thread
// (x-even pair -> same brick, contiguous 32 B).
// ---------------------------------------------------------------------------
__global__ __launch_bounds__(256) void pack_kernel(
    const float* __restrict__ dens,
    const float* __restrict__ sh,
    uint4* __restrict__ vol,
    int V)
{
    int t = blockIdx.x * blockDim.x + threadIdx.x;
    int v0 = t * 2;
    if (v0 >= V) return;

    float2 dd = *reinterpret_cast<const float2*>(dens + v0);
    float sa[27], sb[27];
#pragma unroll
    for (int q = 0; q < 27; ++q) {
        float2 s2 = *reinterpret_cast<const float2*>(sh + (size_t)q * (size_t)V + v0);
        sa[q] = s2.x;
        sb[q] = s2.y;
    }

    int x = v0 & (GR - 1);
    int y = (v0 >> 7) & (GR - 1);
    int z = v0 >> 14;
    int base = brick_addr(x, y, z);          // x even -> pair contiguous

#pragma unroll
    for (int j = 0; j < 2; ++j) {
        const float* sv = (j == 0) ? sa : sb;
        float dv = (j == 0) ? dd.x : dd.y;

        float mp = 0.0f, mn = 0.0f;
#pragma unroll
        for (int q = 0; q < 27; ++q) {
            float xq = sv[q];
            mp = fmaxf(mp, xq);
            mn = fmaxf(mn, -xq);
        }
        float tq = fmaxf(fmaxf(mp * (1.0f / 7.0f), mn * 0.125f), 7.5e-9f);
        int ex = (int)((__float_as_uint(tq) >> 23) & 0xFFu) - 126;
        int e = min(max(ex + 14, 0), 15);
        float invf = __uint_as_float((unsigned int)(141 - e) << 23);  // 2^(14-e)

        unsigned int w[4];
#pragma unroll
        for (int d = 0; d < 3; ++d) {
            unsigned int acc = 0;
#pragma unroll
            for (int b = 0; b < 8; ++b) {
                int n = (int)rintf(sv[8 * d + b] * invf) + 8;
                n = min(max(n, 0), 15);
                acc |= (unsigned int)n << (4 * b);
            }
            w[d] = acc;
        }
        int n24 = min(max((int)rintf(sv[24] * invf) + 8, 0), 15);
        int n25 = min(max((int)rintf(sv[25] * invf) + 8, 0), 15);
        int n26 = min(max((int)rintf(sv[26] * invf) + 8, 0), 15);
        unsigned int dh = (unsigned int)__half_as_ushort(__float2half_rn(dv));
        w[3] = (unsigned int)n24 | ((unsigned int)n25 << 4) | ((unsigned int)n26 << 8)
             | ((unsigned int)e << 12) | (dh << 16);

        vol[base + j] = make_uint4(w[0], w[1], w[2], w[3]);
    }
}

// ---------------------------------------------------------------------------
// Shade 8 fetched corners -> {density, r, g, b}  (R8-proven math).
// ---------------------------------------------------------------------------
__device__ __forceinline__ fvec4 shade_eval(
    uint4 c000, uint4 c001, uint4 c010, uint4 c011,
    uint4 c100, uint4 c101, uint4 c110, uint4 c111,
    float wx1, float wy1, float wz1,
    float dxv, float dyv, float dzv)
{
    float wx0 = 1.0f - wx1, wy0 = 1.0f - wy1, wz0 = 1.0f - wz1;
    float w000 = wz0 * wy0 * wx0, w001 = wz0 * wy0 * wx1;
    float w010 = wz0 * wy1 * wx0, w011 = wz0 * wy1 * wx1;
    float w100 = wz1 * wy0 * wx0, w101 = wz1 * wy0 * wx1;
    float w110 = wz1 * wy1 * wx0, w111 = wz1 * wy1 * wx1;

    __half2 acc2[15];
#pragma unroll
    for (int p = 0; p < 15; ++p) acc2[p] = u2h2(0u);
    float G = 0.0f, accd = 0.0f;

    #define NIB4(DW, O)                                                        \
    {                                                                          \
        acc2[(O)+0] = __hfma2(g2, u2h2((((DW) << 6) & 0x03C003C0u) | 0x3C003C00u), acc2[(O)+0]); \
        acc2[(O)+1] = __hfma2(g2, u2h2((((DW) << 2) & 0x03C003C0u) | 0x3C003C00u), acc2[(O)+1]); \
        acc2[(O)+2] = __hfma2(g2, u2h2((((DW) >> 2) & 0x03C003C0u) | 0x3C003C00u), acc2[(O)+2]); \
        acc2[(O)+3] = __hfma2(g2, u2h2((((DW) >> 6) & 0x03C003C0u) | 0x3C003C00u), acc2[(O)+3]); \
    }
    #define NIB3(DW, O)                                                        \
    {                                                                          \
        acc2[(O)+0] = __hfma2(g2, u2h2((((DW) << 6) & 0x03C003C0u) | 0x3C003C00u), acc2[(O)+0]); \
        acc2[(O)+1] = __hfma2(g2, u2h2((((DW) << 2) & 0x03C003C0u) | 0x3C003C00u), acc2[(O)+1]); \
        acc2[(O)+2] = __hfma2(g2, u2h2((((DW) >> 2) & 0x03C003C0u) | 0x3C003C00u), acc2[(O)+2]); \
    }
    #define CORNER(C, W)                                                       \
    {                                                                          \
        float w_ = (W);                                                        \
        unsigned int e_ = ((C).w >> 12) & 0xFu;                                \
        float f_ = __uint_as_float((113u + e_) << 23);   /* 2^(e-14) */        \
        float g_ = w_ * f_;                                                    \
        G += g_;                                                               \
        accd = fmaf(w_, __half2float(__ushort_as_half((unsigned short)((C).w >> 16))), accd); \
        __half2 g2 = __float2half2_rn(g_);                                     \
        NIB4((C).x, 0) NIB4((C).y, 4) NIB4((C).z, 8) NIB3((C).w, 12)           \
    }

    CORNER(c000, w000) CORNER(c001, w001) CORNER(c010, w010) CORNER(c011, w011)
    CORNER(c100, w100) CORNER(c101, w101) CORNER(c110, w110) CORNER(c111, w111)
    #undef CORNER
    #undef NIB4
    #undef NIB3

    float c24G = 24.0f * G;
    float sch[27];
#pragma unroll
    for (int d = 0; d < 3; ++d) {
#pragma unroll
        for (int p = 0; p < 4; ++p) {
            float2 f2 = __half22float2(acc2[d * 4 + p]);
            sch[8 * d + p]     = fmaf(16.0f, f2.x, -c24G);
            sch[8 * d + p + 4] = fmaf(16.0f, f2.y, -c24G);
        }
    }
#pragma unroll
    for (int p = 0; p < 3; ++p) {
        float2 f2 = __half22float2(acc2[12 + p]);
        sch[24 + p] = fmaf(16.0f, f2.x, -c24G);
    }

    float xx = dxv*dxv, yy = dyv*dyv, zz = dzv*dzv;
    float bs[9];
    bs[0] = 0.28209479177387814f;
    bs[1] = -0.4886025119029199f * dyv;
    bs[2] =  0.4886025119029199f * dzv;
    bs[3] = -0.4886025119029199f * dxv;
    bs[4] =  1.0925484305920792f * dxv * dyv;
    bs[5] = -1.0925484305920792f * dyv * dzv;
    bs[6] =  0.31539156525252005f * (2.0f*zz - xx - yy);
    bs[7] = -1.0925484305920792f * dxv * dzv;
    bs[8] =  0.5462742152960396f * (xx - yy);

    fvec4 res;
    res.x = fmaxf(accd, 0.0f);
#pragma unroll
    for (int ch = 0; ch < 3; ++ch) {
        float sm = 0.0f;
#pragma unroll
        for (int q = 0; q < 9; ++q) sm = fmaf(sch[ch*9 + q], bs[q], sm);
        if (ch == 0) res.y = sigmoidf_(sm);
        else if (ch == 1) res.z = sigmoidf_(sm);
        else res.w = sigmoidf_(sm);
    }
    return res;
}

// ---------------------------------------------------------------------------
// Main: unsorted sample of brick-ordered volume. Streaming inputs/outputs
// use nontemporal accesses so L2 stays reserved for volume lines.
// ---------------------------------------------------------------------------
__global__ __launch_bounds__(256) void sample_kernel(
    const float* __restrict__ xyz,
    const float* __restrict__ vdirs,
    const uint4* __restrict__ vol,
    float* __restrict__ out,
    int N)
{
    int i = blockIdx.x * blockDim.x + threadIdx.x;
    if (i >= N) return;

    float px = __builtin_nontemporal_load(xyz + 3*i + 0);
    float py = __builtin_nontemporal_load(xyz + 3*i + 1);
    float pz = __builtin_nontemporal_load(xyz + 3*i + 2);

    const float kk = (1.0f / 1.5f) * 0.5f * (float)(GR - 1);
    const float cc = 0.5f * (float)(GR - 1);
    float fx = fminf(fmaxf(fmaf(px, kk, cc), 0.0f), (float)(GR - 1));
    float fy = fminf(fmaxf(fmaf(py, kk, cc), 0.0f), (float)(GR - 1));
    float fz = fminf(fmaxf(fmaf(pz, kk, cc), 0.0f), (float)(GR - 1));
    int x0 = (int)fx, y0 = (int)fy, z0 = (int)fz;
    float wx1 = fx - (float)x0, wy1 = fy - (float)y0, wz1 = fz - (float)z0;
    int x1 = min(x0 + 1, GR - 1);
    int y1 = min(y0 + 1, GR - 1);
    int z1 = min(z0 + 1, GR - 1);

    int a000 = brick_addr(x0, y0, z0);
    int a001 = brick_addr(x1, y0, z0);
    int a010 = brick_addr(x0, y1, z0);
    int a011 = brick_addr(x1, y1, z0);
    int a100 = brick_addr(x0, y0, z1);
    int a101 = brick_addr(x1, y0, z1);
    int a110 = brick_addr(x0, y1, z1);
    int a111 = brick_addr(x1, y1, z1);

    uint4 c000 = vol[a000];
    uint4 c001 = vol[a001];
    uint4 c010 = vol[a010];
    uint4 c011 = vol[a011];
    uint4 c100 = vol[a100];
    uint4 c101 = vol[a101];
    uint4 c110 = vol[a110];
    uint4 c111 = vol[a111];

    float dxv = __builtin_nontemporal_load(vdirs + 3*i + 0);
    float dyv = __builtin_nontemporal_load(vdirs + 3*i + 1);
    float dzv = __builtin_nontemporal_load(vdirs + 3*i + 2);

    fvec4 res = shade_eval(c000, c001, c010, c011, c100, c101, c110, c111,
                           wx1, wy1, wz1, dxv, dyv, dzv);

    __builtin_nontemporal_store(res.x, &out[i]);
    size_t o = (size_t)N + 3*(size_t)i;
    __builtin_nontemporal_store(res.y, &out[o + 0]);
    __builtin_nontemporal_store(res.z, &out[o + 1]);
    __builtin_nontemporal_store(res.w, &out[o + 2]);
}

// ---------------------------------------------------------------------------
// Tiny-ws fallback: direct fp32 channel-major sampling.
// ---------------------------------------------------------------------------
__global__ __launch_bounds__(256) void sample_direct_kernel(
    const float* __restrict__ xyz,
    const float* __restrict__ vdirs,
    const float* __restrict__ dens,
    const float* __restrict__ sh,
    float* __restrict__ out,
    int N)
{
    int i = blockIdx.x * blockDim.x + threadIdx.x;
    if (i >= N) return;

    const float kk = (1.0f / 1.5f) * 0.5f * (float)(GR - 1);
    const float cc = 0.5f * (float)(GR - 1);
    float fx = fminf(fmaxf(fmaf(xyz[3*i+0], kk, cc), 0.0f), (float)(GR - 1));
    float fy = fminf(fmaxf(fmaf(xyz[3*i+1], kk, cc), 0.0f), (float)(GR - 1));
    float fz = fminf(fmaxf(fmaf(xyz[3*i+2], kk, cc), 0.0f), (float)(GR - 1));
    float x0f = floorf(fx), y0f = floorf(fy), z0f = floorf(fz);
    float wx1 = fx - x0f, wy1 = fy - y0f, wz1 = fz - z0f;
    int x0 = (int)x0f, y0 = (int)y0f, z0 = (int)z0f;
    float wx[2] = { 1.0f - wx1, wx1 };
    float wy[2] = { 1.0f - wy1, wy1 };
    float wz[2] = { 1.0f - wz1, wz1 };
    int xi[2] = { x0, min(x0 + 1, GR-1) };
    int yi[2] = { y0, min(y0 + 1, GR-1) };
    int zi[2] = { z0, min(z0 + 1, GR-1) };

    const size_t V = (size_t)GR * GR * GR;
    float acc[NCH];
#pragma unroll
    for (int c = 0; c < NCH; ++c) acc[c] = 0.0f;

#pragma unroll
    for (int dz = 0; dz < 2; ++dz)
#pragma unroll
        for (int dy = 0; dy < 2; ++dy)
#pragma unroll
            for (int dx = 0; dx < 2; ++dx) {
                float w = wz[dz] * wy[dy] * wx[dx];
                size_t vox = (((size_t)zi[dz] * GR) + yi[dy]) * GR + xi[dx];
                acc[0] = fmaf(w, dens[vox], acc[0]);
#pragma unroll
                for (int c = 0; c < 27; ++c)
                    acc[1 + c] = fmaf(w, sh[(size_t)c * V + vox], acc[1 + c]);
            }

    float dxv = vdirs[3*i+0], dyv = vdirs[3*i+1], dzv = vdirs[3*i+2];
    float xx = dxv*dxv, yy = dyv*dyv, zz = dzv*dzv;
    float b[9];
    b[0] = 0.28209479177387814f;
    b[1] = -0.4886025119029199f * dyv;
    b[2] =  0.4886025119029199f * dzv;
    b[3] = -0.4886025119029199f * dxv;
    b[4] =  1.0925484305920792f * dxv * dyv;
    b[5] = -1.0925484305920792f * dyv * dzv;
    b[6] =  0.31539156525252005f * (2.0f*zz - xx - yy);
    b[7] = -1.0925484305920792f * dxv * dzv;
    b[8] =  0.5462742152960396f * (xx - yy);

    out[i] = fmaxf(acc[0], 0.0f);
#pragma unroll
    for (int c = 0; c < 3; ++c) {
        float sm = 0.0f;
#pragma unroll
        for (int q = 0; q < 9; ++q) sm = fmaf(acc[1 + c*9 + q], b[q], sm);
        out[(size_t)N + 3*(size_t)i + c] = sigmoidf_(sm);
    }
}

extern "C" void kernel_launch(void* const* d_in, const int* in_sizes, int n_in,
                              void* d_out, int out_size, void* d_ws, size_t ws_size,
                              hipStream_t stream) {
    const float* xyz   = (const float*)d_in[0];
    const float* vdirs = (const float*)d_in[1];
    const float* dens  = (const float*)d_in[2];
    const float* sh    = (const float*)d_in[3];
    float* out = (float*)d_out;

    int N = in_sizes[0] / 3;
    const int V = GR * GR * GR;
    size_t need = (size_t)V * 16;        // 33.5 MB packed volume

    if (ws_size >= need) {
        uint4* vol = (uint4*)d_ws;
        pack_kernel<<<(V / 2 + 255) / 256, 256, 0, stream>>>(dens, sh, vol, V);
        sample_kernel<<<(N + 255) / 256, 256, 0, stream>>>(xyz, vdirs, vol, out, N);
    } else {
        sample_direct_kernel<<<(N + 255) / 256, 256, 0, stream>>>(xyz, vdirs, dens, sh, out, N);
    }
}